// Round 10
// baseline (717.762 us; speedup 1.0000x reference)
//
#include <hip/hip_runtime.h>
#include <hip/hip_bf16.h>
#include <stdint.h>

// TransformerEncoder on MI355X. B=2,S=2048,D=512,H=8,DH=64,F=2048,L=6.
// R17: attn QBLK 64->128 (8 waves, 512 thr/block). Halves K/V+mask refetch
//      (each tile staged once per 128 q-rows), one glds16 per tile (512
//      lanes x 16B = full 8KB tile), LDS 34KB -> 4 blocks/CU x 8 waves =
//      32 waves/CU (was 24). Grid 1024 = 4/CU exact. Per-wave inner loop
//      byte-identical to R16. qkv fusion + T1 + dbuf GEMMs unchanged (R16).

typedef __bf16 bf16x8 __attribute__((ext_vector_type(8)));
typedef __bf16 bf16x4 __attribute__((ext_vector_type(4)));
typedef float f32x4 __attribute__((ext_vector_type(4)));
typedef unsigned short u16;
typedef unsigned short u16x8 __attribute__((ext_vector_type(8)));

#define NB 2
#define NS 2048
#define ND 512
#define NH 8
#define NDH 64
#define NF 2048
#define NL 6
#define NCHUNK 4
#define CK (NS / NCHUNK)  // 512 keys per chunk
#define LOG2E 1.4426950408889634f
#define QSCALE (0.125f * LOG2E)

#if defined(__has_builtin)
#if __has_builtin(__builtin_amdgcn_global_load_lds)
#define HAVE_GLDS 1
#endif
#endif
#ifndef HAVE_GLDS
#define HAVE_GLDS 0
#endif

#if HAVE_GLDS
__device__ __forceinline__ void glds16(const u16* g, u16* l) {
  __builtin_amdgcn_global_load_lds(
      (const __attribute__((address_space(1))) unsigned int*)g,
      (__attribute__((address_space(3))) unsigned int*)l, 16, 0, 0);
}
#endif

__device__ __forceinline__ u16 f2bf(float f) {
  unsigned u = __float_as_uint(f);
  u += 0x7FFFu + ((u >> 16) & 1u);
  return (u16)(u >> 16);
}

// XCD-chunked bijection: hw id w (round-robin across 8 XCDs) -> logical id
// such that each XCD owns a CONTIGUOUS logical range. Requires n % 8 == 0.
__device__ __forceinline__ int xswz(int w, int n) {
  return (w & 7) * (n >> 3) + (w >> 3);
}

// ---------------- weight convert + transpose: f32 [K,N] -> bf16 [N,K] ------
__global__ __launch_bounds__(256) void wcvt_t(const float* __restrict__ src,
                                              u16* __restrict__ dst,
                                              int K, int N) {
  __shared__ float tile[32][33];
  int l = blockIdx.z;
  const float* s = src + (size_t)l * K * N;
  u16* d = dst + (size_t)l * K * N;
  int k0 = blockIdx.y * 32, n0 = blockIdx.x * 32;
  int tx = threadIdx.x, ty = threadIdx.y;  // 32x8
  for (int i = 0; i < 32; i += 8)
    tile[ty + i][tx] = s[(size_t)(k0 + ty + i) * N + n0 + tx];
  __syncthreads();
  for (int i = 0; i < 32; i += 8)
    d[(size_t)(n0 + ty + i) * K + k0 + tx] = f2bf(tile[tx][ty + i]);
}

// ---------------- LayerNorm: fp32 in, bf16 (or f32) out --------------------
template <int OUT_BF16>
__global__ __launch_bounds__(256) void ln_k(const float* __restrict__ x,
                                            const float* __restrict__ w,
                                            const float* __restrict__ b,
                                            void* __restrict__ out) {
  int row = blockIdx.x;
  int t = threadIdx.x;  // 256 threads, D=512 -> one float2 each
  const float* xr = x + (size_t)row * ND;
  float2 v = ((const float2*)xr)[t];
  float s = v.x + v.y, ss = v.x * v.x + v.y * v.y;
  for (int o = 32; o > 0; o >>= 1) {
    s += __shfl_down(s, o);
    ss += __shfl_down(ss, o);
  }
  __shared__ float rs[4], rss[4];
  if ((t & 63) == 0) { rs[t >> 6] = s; rss[t >> 6] = ss; }
  __syncthreads();
  float S = rs[0] + rs[1] + rs[2] + rs[3];
  float SS = rss[0] + rss[1] + rss[2] + rss[3];
  float mean = S * (1.0f / ND);
  float var = SS * (1.0f / ND) - mean * mean;
  float rstd = rsqrtf(var + 1e-5f);
  float2 wv = ((const float2*)w)[t];
  float2 bv = ((const float2*)b)[t];
  float y0 = (v.x - mean) * rstd * wv.x + bv.x;
  float y1 = (v.y - mean) * rstd * wv.y + bv.y;
  if (OUT_BF16) {
    ushort2 p; p.x = f2bf(y0); p.y = f2bf(y1);
    ((ushort2*)out)[(size_t)row * (ND / 2) + t] = p;
  } else {
    float2 p; p.x = y0; p.y = y1;
    ((float2*)out)[(size_t)row * (ND / 2) + t] = p;
  }
}

// ---------------- GEMM body: C[M,N] = A[M,K](bf16) @ Bt[N,K]^T + bias ------
// EPI: 0 = bf16 out (bias per col), 1 = relu -> bf16, 2 = +resid -> f32,
//      3 = bf16 out, bias per ROW (V-transposed GEMM)
// flat = logical block id in a gx*gy grid (T1-swizzled inside).
// sm = LDS arena, 2*BM*BK + 2*BN*BK u16 (double-buffered A then B).
template <int EPI, int BM, int BN, int BK>
__device__ __forceinline__ void gemm_body(int flat, int gx, int gy,
                                          const u16* __restrict__ A,
                                          const u16* __restrict__ Bt,
                                          const float* __restrict__ bias,
                                          const float* __restrict__ resid,
                                          void* __restrict__ C,
                                          int M, int N, int K, int lda,
                                          u16* sm) {
  constexpr int MT = BM / 32;       // m-frags per wave
  constexpr int NT = BN / 32;       // n-frags per wave
  constexpr int CB = BK / 8;        // colblocks (8 or 16)
  constexpr int RPP = 2048 / BK;    // rows staged per pass (32 or 16)
  constexpr int AP = BM / RPP;      // staging passes
  constexpr int BP = BN / RPP;
  constexpr int KK = BK / 32;       // k-subtiles per buffer
  constexpr int LAU = BM * BK;      // one A buffer, u16
  constexpr int LBU = BN * BK;
  int s_id = xswz(flat, gx * gy);
  int bn = s_id % gx, bm = s_id / gx;
  int t = threadIdx.x;
  int wave = t >> 6, lane = t & 63, quad = lane >> 4, l15 = lane & 15;
  int wm = (wave >> 1) * (BM / 2), wn = (wave & 1) * (BN / 2);
  f32x4 acc[MT][NT] = {};
  int srow = t / CB;
  int scol = ((t % CB) ^ (srow & (CB - 1))) * 8;  // swizzled global colblk
  const u16* Ag = A + (size_t)(bm * BM) * lda;
  const u16* Bg = Bt + (size_t)(bn * BN) * lda;

  auto stage = [&](int k0, int buf) {
    u16* laB = sm + buf * LAU;
    u16* lbB = sm + 2 * LAU + buf * LBU;
#if HAVE_GLDS
    u16* laW = laB + wave * 512;  // lane i -> +16B*i
    u16* lbW = lbB + wave * 512;
#pragma unroll
    for (int g = 0; g < AP; g++)
      glds16(&Ag[(size_t)(srow + g * RPP) * lda + k0 + scol], laW + g * 2048);
#pragma unroll
    for (int g = 0; g < BP; g++)
      glds16(&Bg[(size_t)(srow + g * RPP) * lda + k0 + scol], lbW + g * 2048);
#else
#pragma unroll
    for (int g = 0; g < AP; g++)
      *(bf16x8*)&laB[(srow + g * RPP) * BK + (t % CB) * 8] =
          *(const bf16x8*)&Ag[(size_t)(srow + g * RPP) * lda + k0 + scol];
#pragma unroll
    for (int g = 0; g < BP; g++)
      *(bf16x8*)&lbB[(srow + g * RPP) * BK + (t % CB) * 8] =
          *(const bf16x8*)&Bg[(size_t)(srow + g * RPP) * lda + k0 + scol];
#endif
  };

  stage(0, 0);  // prologue
  const int nk = K / BK;
  int cur = 0;
  for (int ks = 0; ks < nk; ks++) {
    __syncthreads();  // buf[cur] staged & visible
    if (ks + 1 < nk) stage((ks + 1) * BK, cur ^ 1);
    const u16* lac = sm + cur * LAU;
    const u16* lbc = sm + 2 * LAU + cur * LBU;
#pragma unroll
    for (int kk = 0; kk < KK; kk++) {
      bf16x8 af[MT], bfr[NT];
#pragma unroll
      for (int i = 0; i < MT; i++) {
        int row = wm + i * 16 + l15;
        af[i] = *(const bf16x8*)&lac[row * BK + ((kk * 4 + quad) ^ (row & (CB - 1))) * 8];
      }
#pragma unroll
      for (int i = 0; i < NT; i++) {
        int row = wn + i * 16 + l15;
        bfr[i] = *(const bf16x8*)&lbc[row * BK + ((kk * 4 + quad) ^ (row & (CB - 1))) * 8];
      }
#pragma unroll
      for (int mt = 0; mt < MT; mt++)
#pragma unroll
        for (int nt = 0; nt < NT; nt++)
          acc[mt][nt] = __builtin_amdgcn_mfma_f32_16x16x32_bf16(
              af[mt], bfr[nt], acc[mt][nt], 0, 0, 0);
    }
    cur ^= 1;
  }
#pragma unroll
  for (int mt = 0; mt < MT; mt++)
#pragma unroll
    for (int nt = 0; nt < NT; nt++) {
      int col = bn * BN + wn + nt * 16 + l15;
      float bcol = (EPI == 3) ? 0.f : bias[col];
#pragma unroll
      for (int r = 0; r < 4; r++) {
        int row = bm * BM + wm + mt * 16 + quad * 4 + r;
        float v = acc[mt][nt][r] + ((EPI == 3) ? bias[row] : bcol);
        if (EPI == 1) v = fmaxf(v, 0.f);
        if (EPI == 2)
          ((float*)C)[(size_t)row * N + col] = v + resid[(size_t)row * N + col];
        else
          ((u16*)C)[(size_t)row * N + col] = f2bf(v);
      }
    }
}

// Standalone GEMM kernel (per-instantiation LDS sizing)
template <int EPI, int BM, int BN, int BK>
__global__ __launch_bounds__(256) void gemm_bt(const u16* __restrict__ A,
                                               const u16* __restrict__ Bt,
                                               const float* __restrict__ bias,
                                               const float* __restrict__ resid,
                                               void* __restrict__ C,
                                               int M, int N, int K, int lda) {
  __shared__ __align__(16) u16 sm[2 * BM * BK + 2 * BN * BK];
  int flat = blockIdx.x + gridDim.x * blockIdx.y;
  gemm_body<EPI, BM, BN, BK>(flat, gridDim.x, gridDim.y, A, Bt, bias, resid,
                             C, M, N, K, lda, sm);
}

// Fused QK-proj + V^T-proj: two independent GEMMs, one dispatch (1024 blocks)
__global__ __launch_bounds__(256) void qkv_k(const u16* __restrict__ ybuf,
                                             const u16* __restrict__ wq_l,
                                             const float* __restrict__ inb_l,
                                             u16* __restrict__ qk,
                                             u16* __restrict__ vtb) {
  __shared__ __align__(16) u16 sm[32768];  // 64 KB arena (max of both bodies)
  int f = blockIdx.x;
  if (f < 512) {
    // Q|K projection: [4096,1024] = ybuf[4096,512] @ wq[0:1024]^T, 64x128xBK64
    gemm_body<0, 64, 128, 64>(f, 2 * ND / 128, NB * NS / 64, ybuf, wq_l,
                              inb_l, nullptr, qk, NB * NS, 2 * ND, ND, ND, sm);
  } else {
    // V projection, transposed out: [512,4096] = wv[512,512] @ ybuf^T, 64x64xBK128
    gemm_body<3, 64, 64, 128>(f - 512, NB * NS / 64, ND / 64,
                              wq_l + (size_t)2 * ND * ND, ybuf,
                              inb_l + 2 * ND, nullptr, vtb, ND, NB * NS, ND,
                              ND, sm);
  }
}

// ---------------- Flash attention, split-KV, no-max softmax (R17) ----------
// qk: [B*S, 2*D] bf16 (q|k per token). vt: [D, B*S] bf16 (row=h*64+dh).
// QBLK=128: 8 waves x 16 q-rows. Swapped QK^T (mfma(K,Q)); mask (xLOG2E) is
// the MFMA C-init. P: 4x ds_write_b64 per wave into p_s[wave]; PV A-frag one
// ds_read_b128 per kk. One glds16 per K/V tile (512 lanes = 8KB tile).
// LDS 34KB -> 4 blocks/CU x 8 waves = 32 waves/CU. Grid 1024 = 4/CU exact.
__global__ __launch_bounds__(512) void attn_k(const u16* __restrict__ qk,
                                              const u16* __restrict__ vt,
                                              const float* __restrict__ mask,
                                              u16* __restrict__ opart,
                                              float* __restrict__ lbuf) {
  __shared__ u16 kt_s[64 * 64];    // K tile, swizzled
  __shared__ u16 vt_s[64 * 64];    // V^T tile, swizzled
  __shared__ u16 p_s[8][16 * 64];  // per-wave P[q][k], 16B-block XOR swizzle
  __shared__ float mask_s[CK];     // chunk mask * LOG2E
  // hw flat id (x fastest) -> XCD-chunked logical (qt, bh, c)
  int flat = blockIdx.x + 16 * (blockIdx.y + 16 * blockIdx.z);
  int s_id = xswz(flat, 16 * 16 * NCHUNK);
  int qt = s_id & 15;
  int bh = (s_id >> 4) & 15;
  int c = s_id >> 8;
  int b = bh >> 3, h = bh & 7;
  int t = threadIdx.x;
  int wave = t >> 6, lane = t & 63, quad = lane >> 4, l15 = lane & 15;

  // stage chunk mask once (first __syncthreads in the loop orders it)
  {
    const float* mrow = mask + b * NS + c * CK;
    mask_s[t] = mrow[t] * LOG2E;
  }

  int qrow = qt * 128 + wave * 16 + l15;
  const u16* qbase = qk + ((size_t)(b * NS + qrow)) * (2 * ND) + h * NDH;
  bf16x8 qf[2];
  qf[0] = *(const bf16x8*)&qbase[quad * 8];
  qf[1] = *(const bf16x8*)&qbase[32 + quad * 8];
#pragma unroll
  for (int e = 0; e < 8; e++) {
    qf[0][e] = (__bf16)((float)qf[0][e] * QSCALE);
    qf[1][e] = (__bf16)((float)qf[1][e] * QSCALE);
  }
  bf16x8 ones;
#pragma unroll
  for (int e = 0; e < 8; e++) ones[e] = (__bf16)1.0f;

  f32x4 oacc[4] = {};
  f32x4 ls = {};  // row-sums of P (all 16 cols identical)

  int srow8 = t >> 3;                          // [0,64): tile row
  int segsw = ((t & 7) ^ ((t >> 3) & 7)) * 8;  // swizzled fetch colblk
  const u16* kg0 = qk + ((size_t)(b * NS + srow8)) * (2 * ND) + ND + h * NDH + segsw;
  const u16* vg0 = vt + ((size_t)(h * NDH + srow8)) * (NB * NS) + b * NS + segsw;
#if HAVE_GLDS
  u16* ktB = kt_s + wave * 512;  // 8 waves x 1KB = full 8KB tile
  u16* vtB = vt_s + wave * 512;
#endif
  u16* pw = &p_s[wave][0];
  int l7 = l15 & 7;
  for (int kt0 = c * CK; kt0 < (c + 1) * CK; kt0 += 64) {
    __syncthreads();
#if HAVE_GLDS
    glds16(&kg0[(size_t)kt0 * (2 * ND)], ktB);
    glds16(&vg0[kt0], vtB);
#else
    *(bf16x8*)&kt_s[srow8 * 64 + (t & 7) * 8] =
        *(const bf16x8*)&kg0[(size_t)kt0 * (2 * ND)];
    *(bf16x8*)&vt_s[srow8 * 64 + (t & 7) * 8] = *(const bf16x8*)&vg0[kt0];
#endif
    __syncthreads();
    // S^T = K @ Q^T, C-initialized with the mask (already *LOG2E).
    int ktl = kt0 - c * CK;
    f32x4 sc[4];
#pragma unroll
    for (int nt = 0; nt < 4; nt++)
      sc[nt] = *(const f32x4*)&mask_s[ktl + nt * 16 + quad * 4];
#pragma unroll
    for (int nt = 0; nt < 4; nt++) {
      int row = nt * 16 + l15;
      bf16x8 kf0 = *(const bf16x8*)&kt_s[row * 64 + (quad ^ (row & 7)) * 8];
      bf16x8 kf1 = *(const bf16x8*)&kt_s[row * 64 + ((quad + 4) ^ (row & 7)) * 8];
      sc[nt] = __builtin_amdgcn_mfma_f32_16x16x32_bf16(kf0, qf[0], sc[nt], 0, 0, 0);
      sc[nt] = __builtin_amdgcn_mfma_f32_16x16x32_bf16(kf1, qf[1], sc[nt], 0, 0, 0);
    }
    // p = exp2(sc); pack k-contiguous bf16x4, one b64 store per nt.
#pragma unroll
    for (int nt = 0; nt < 4; nt++) {
      float2 plo, phi;
      plo.x = __builtin_amdgcn_exp2f(sc[nt][0]);
      plo.y = __builtin_amdgcn_exp2f(sc[nt][1]);
      phi.x = __builtin_amdgcn_exp2f(sc[nt][2]);
      phi.y = __builtin_amdgcn_exp2f(sc[nt][3]);
      __hip_bfloat162 b01 = __float22bfloat162_rn(plo);
      __hip_bfloat162 b23 = __float22bfloat162_rn(phi);
      uint2 pk;
      pk.x = *reinterpret_cast<unsigned int*>(&b01);
      pk.y = *reinterpret_cast<unsigned int*>(&b23);
      int cb = nt * 2 + (quad >> 1);                  // logical 8-k block
      int col = ((cb ^ l7) << 3) + (quad & 1) * 4;    // swizzled column
      *reinterpret_cast<uint2*>(&pw[l15 * 64 + col]) = pk;
    }
    asm volatile("s_waitcnt lgkmcnt(0)" ::: "memory");
    // O += P @ V ; l += P @ ones
#pragma unroll
    for (int kk = 0; kk < 2; kk++) {
      int cbr = kk * 4 + quad;
      bf16x8 pf = *(const bf16x8*)&pw[l15 * 64 + ((cbr ^ l7) << 3)];
#pragma unroll
      for (int nt = 0; nt < 4; nt++) {
        int row = nt * 16 + l15;
        bf16x8 vf = *(const bf16x8*)&vt_s[row * 64 + ((kk * 4 + quad) ^ (row & 7)) * 8];
        oacc[nt] = __builtin_amdgcn_mfma_f32_16x16x32_bf16(pf, vf, oacc[nt], 0, 0, 0);
      }
      ls = __builtin_amdgcn_mfma_f32_16x16x32_bf16(pf, ones, ls, 0, 0, 0);
    }
  }
  // store un-normalized partial O (bf16) + l per row
  u16* ob = opart + (((size_t)(c * NB * NH + bh) * NS) + qt * 128 + wave * 16) * NDH;
#pragma unroll
  for (int nt = 0; nt < 4; nt++)
#pragma unroll
    for (int r = 0; r < 4; r++)
      ob[(size_t)(quad * 4 + r) * NDH + nt * 16 + l15] = f2bf(oacc[nt][r]);
  if (l15 == 0) {
    size_t li = (size_t)(c * NB * NH + bh) * NS + qt * 128 + wave * 16 + quad * 4;
#pragma unroll
    for (int r = 0; r < 4; r++) lbuf[li + r] = ls[r];
  }
}

// ---------------- merge split-KV partials -> o [B*S, D] bf16 ---------------
__global__ __launch_bounds__(256) void attn_merge(const u16* __restrict__ opart,
                                                  const float* __restrict__ lbuf,
                                                  u16* __restrict__ o) {
  int gt = blockIdx.x * 256 + threadIdx.x;  // [0, 16*2048*8)
  int grp = gt & 7;
  int s = (gt >> 3) & (NS - 1);
  int bh = gt >> 14;
  float L = 0.f;
#pragma unroll
  for (int c = 0; c < NCHUNK; c++)
    L += lbuf[(size_t)(c * NB * NH + bh) * NS + s];
  float inv = 1.0f / L;
  float acc[8] = {};
#pragma unroll
  for (int c = 0; c < NCHUNK; c++) {
    bf16x8 ov = *(const bf16x8*)&opart[((size_t)(c * NB * NH + bh) * NS + s) * NDH + grp * 8];
#pragma unroll
    for (int j = 0; j < 8; j++) acc[j] += (float)ov[j];
  }
  u16x8 res;
#pragma unroll
  for (int j = 0; j < 8; j++) res[j] = f2bf(acc[j] * inv);
  int b = bh >> 3, h = bh & 7;
  *(u16x8*)&o[((size_t)(b * NS + s)) * ND + h * NDH + grp * 8] = res;
}

// ---------------------------------------------------------------------------
extern "C" void kernel_launch(void* const* d_in, const int* in_sizes, int n_in,
                              void* d_out, int out_size, void* d_ws, size_t ws_size,
                              hipStream_t stream) {
  const float* x = (const float*)d_in[0];
  const float* mask = (const float*)d_in[1];
  const float* ln1w = (const float*)d_in[2];
  const float* ln1b = (const float*)d_in[3];
  const float* in_w = (const float*)d_in[4];
  const float* in_b = (const float*)d_in[5];
  const float* out_w = (const float*)d_in[6];
  const float* out_b = (const float*)d_in[7];
  const float* ln2w = (const float*)d_in[8];
  const float* ln2b = (const float*)d_in[9];
  const float* f1w = (const float*)d_in[10];
  const float* f1b = (const float*)d_in[11];
  const float* f2w = (const float*)d_in[12];
  const float* f2b = (const float*)d_in[13];
  const float* normw = (const float*)d_in[14];
  const float* normb = (const float*)d_in[15];

  char* ws = (char*)d_ws;
  auto carve = [&](size_t bytes) {
    char* p = ws;
    ws += (bytes + 255) & ~(size_t)255;
    return p;
  };
  u16* wq_t = (u16*)carve((size_t)NL * 3 * ND * ND * 2);   // [L][3D][D]
  u16* wo_t = (u16*)carve((size_t)NL * ND * ND * 2);       // [L][D][D]
  u16* w1_t = (u16*)carve((size_t)NL * NF * ND * 2);       // [L][F][D]
  u16* w2_t = (u16*)carve((size_t)NL * ND * NF * 2);       // [L][D][F]
  u16* ybuf = (u16*)carve((size_t)NB * NS * ND * 2);
  u16* qk = (u16*)carve((size_t)NB * NS * 2 * ND * 2);     // [M][2D]
  u16* vtb = (u16*)carve((size_t)ND * NB * NS * 2);        // [D][M]
  u16* obuf = (u16*)carve((size_t)NB * NS * ND * 2);
  u16* ubuf = (u16*)carve((size_t)NB * NS * NF * 2);       // FFN mid; aliased by opart
  float* hA = (float*)carve((size_t)NB * NS * ND * 4);
  float* hB = (float*)carve((size_t)NB * NS * ND * 4);
  float* lbuf = (float*)carve((size_t)NCHUNK * NB * NH * NS * 4);
  u16* opart = ubuf;  // same size (16.8 MB), disjoint lifetime within a layer

  const int M = NB * NS;  // 4096
  dim3 tb(32, 8);
  wcvt_t<<<dim3(3 * ND / 32, ND / 32, NL), tb, 0, stream>>>(in_w, wq_t, ND, 3 * ND);
  wcvt_t<<<dim3(ND / 32, ND / 32, NL), tb, 0, stream>>>(out_w, wo_t, ND, ND);
  wcvt_t<<<dim3(NF / 32, ND / 32, NL), tb, 0, stream>>>(f1w, w1_t, ND, NF);
  wcvt_t<<<dim3(ND / 32, NF / 32, NL), tb, 0, stream>>>(f2w, w2_t, NF, ND);

  const float* hin = x;
  for (int l = 0; l < NL; l++) {
    ln_k<1><<<M, 256, 0, stream>>>(hin, ln1w + l * ND, ln1b + l * ND, ybuf);
    // Fused Q|K projection + V^T projection: 1024 blocks, one dispatch
    qkv_k<<<1024, 256, 0, stream>>>(ybuf, wq_t + (size_t)l * 3 * ND * ND,
                                    in_b + (size_t)l * 3 * ND, qk, vtb);
    // attn: QBLK=128, 512 threads, grid 16x16x4 = 1024 blocks
    attn_k<<<dim3(NS / 128, NB * NH, NCHUNK), 512, 0, stream>>>(
        qk, vtb, mask, opart, lbuf);
    attn_merge<<<(NB * NH * NS * 8) / 256, 256, 0, stream>>>(opart, lbuf, obuf);
    // O projection: [4096,512] -- 64x64xBK128 dbuf, grid 512
    gemm_bt<2, 64, 64, 128><<<dim3(ND / 64, M / 64), 256, 0, stream>>>(
        obuf, wo_t + (size_t)l * ND * ND, out_b + l * ND, hin, hB, M, ND, ND, ND);
    ln_k<1><<<M, 256, 0, stream>>>(hB, ln2w + l * ND, ln2b + l * ND, ybuf);
    // FFN1: [4096,2048] -- 128x128xBK64 dbuf, grid 512
    gemm_bt<1, 128, 128, 64><<<dim3(NF / 128, M / 128), 256, 0, stream>>>(
        ybuf, w1_t + (size_t)l * NF * ND, f1b + l * NF, nullptr, ubuf,
        M, NF, ND, ND);
    // FFN2: [4096,512] -- 64x64xBK128 dbuf, grid 512
    gemm_bt<2, 64, 64, 128><<<dim3(ND / 64, M / 64), 256, 0, stream>>>(
        ubuf, w2_t + (size_t)l * ND * NF, f2b + l * ND, hB, hA, M, ND, NF, NF);
    hin = hA;
  }
  ln_k<0><<<M, 256, 0, stream>>>(hA, normw, normb, (float*)d_out);
}

// Round 11
// 708.499 us; speedup vs baseline: 1.0131x; 1.0131x over previous
//
#include <hip/hip_runtime.h>
#include <hip/hip_bf16.h>
#include <stdint.h>

// TransformerEncoder on MI355X. B=2,S=2048,D=512,H=8,DH=64,F=2048,L=6.
// R18: attn rewritten on mfma_f32_32x32x16_bf16 (4 waves x 32 q). Doubles
//      MACs per LDS byte (attn measured LDS-pipe-bound: R17's occupancy/
//      fetch changes were null). P never touches LDS: swapped QK^T leaves
//      P[key][q] reg-resident; PV A-frags rebuilt via cvt_pk pairs + one
//      __shfl_xor(.,32) half-exchange (T12). Row-sums via VALU (+1 shfl),
//      ones-MFMA dropped. C layout col=lane&31,row=(reg&3)+8(reg>>2)+4(l>>5)
//      [m74/m101]. Staging/swizzle/split-KV/merge/GEMMs/qkv/T1 unchanged.

typedef __bf16 bf16x8 __attribute__((ext_vector_type(8)));
typedef __bf16 bf16x4 __attribute__((ext_vector_type(4)));
typedef float f32x4 __attribute__((ext_vector_type(4)));
typedef float f32x16 __attribute__((ext_vector_type(16)));
typedef unsigned short u16;
typedef unsigned short u16x8 __attribute__((ext_vector_type(8)));

#define NB 2
#define NS 2048
#define ND 512
#define NH 8
#define NDH 64
#define NF 2048
#define NL 6
#define NCHUNK 4
#define CK (NS / NCHUNK)  // 512 keys per chunk
#define LOG2E 1.4426950408889634f
#define QSCALE (0.125f * LOG2E)

#if defined(__has_builtin)
#if __has_builtin(__builtin_amdgcn_global_load_lds)
#define HAVE_GLDS 1
#endif
#endif
#ifndef HAVE_GLDS
#define HAVE_GLDS 0
#endif

#if HAVE_GLDS
__device__ __forceinline__ void glds16(const u16* g, u16* l) {
  __builtin_amdgcn_global_load_lds(
      (const __attribute__((address_space(1))) unsigned int*)g,
      (__attribute__((address_space(3))) unsigned int*)l, 16, 0, 0);
}
#endif

__device__ __forceinline__ u16 f2bf(float f) {
  unsigned u = __float_as_uint(f);
  u += 0x7FFFu + ((u >> 16) & 1u);
  return (u16)(u >> 16);
}

// XCD-chunked bijection: hw id w (round-robin across 8 XCDs) -> logical id
// such that each XCD owns a CONTIGUOUS logical range. Requires n % 8 == 0.
__device__ __forceinline__ int xswz(int w, int n) {
  return (w & 7) * (n >> 3) + (w >> 3);
}

// ---------------- weight convert + transpose: f32 [K,N] -> bf16 [N,K] ------
__global__ __launch_bounds__(256) void wcvt_t(const float* __restrict__ src,
                                              u16* __restrict__ dst,
                                              int K, int N) {
  __shared__ float tile[32][33];
  int l = blockIdx.z;
  const float* s = src + (size_t)l * K * N;
  u16* d = dst + (size_t)l * K * N;
  int k0 = blockIdx.y * 32, n0 = blockIdx.x * 32;
  int tx = threadIdx.x, ty = threadIdx.y;  // 32x8
  for (int i = 0; i < 32; i += 8)
    tile[ty + i][tx] = s[(size_t)(k0 + ty + i) * N + n0 + tx];
  __syncthreads();
  for (int i = 0; i < 32; i += 8)
    d[(size_t)(n0 + ty + i) * K + k0 + tx] = f2bf(tile[tx][ty + i]);
}

// ---------------- LayerNorm: fp32 in, bf16 (or f32) out --------------------
template <int OUT_BF16>
__global__ __launch_bounds__(256) void ln_k(const float* __restrict__ x,
                                            const float* __restrict__ w,
                                            const float* __restrict__ b,
                                            void* __restrict__ out) {
  int row = blockIdx.x;
  int t = threadIdx.x;  // 256 threads, D=512 -> one float2 each
  const float* xr = x + (size_t)row * ND;
  float2 v = ((const float2*)xr)[t];
  float s = v.x + v.y, ss = v.x * v.x + v.y * v.y;
  for (int o = 32; o > 0; o >>= 1) {
    s += __shfl_down(s, o);
    ss += __shfl_down(ss, o);
  }
  __shared__ float rs[4], rss[4];
  if ((t & 63) == 0) { rs[t >> 6] = s; rss[t >> 6] = ss; }
  __syncthreads();
  float S = rs[0] + rs[1] + rs[2] + rs[3];
  float SS = rss[0] + rss[1] + rss[2] + rss[3];
  float mean = S * (1.0f / ND);
  float var = SS * (1.0f / ND) - mean * mean;
  float rstd = rsqrtf(var + 1e-5f);
  float2 wv = ((const float2*)w)[t];
  float2 bv = ((const float2*)b)[t];
  float y0 = (v.x - mean) * rstd * wv.x + bv.x;
  float y1 = (v.y - mean) * rstd * wv.y + bv.y;
  if (OUT_BF16) {
    ushort2 p; p.x = f2bf(y0); p.y = f2bf(y1);
    ((ushort2*)out)[(size_t)row * (ND / 2) + t] = p;
  } else {
    float2 p; p.x = y0; p.y = y1;
    ((float2*)out)[(size_t)row * (ND / 2) + t] = p;
  }
}

// ---------------- GEMM body: C[M,N] = A[M,K](bf16) @ Bt[N,K]^T + bias ------
// EPI: 0 = bf16 out (bias per col), 1 = relu -> bf16, 2 = +resid -> f32,
//      3 = bf16 out, bias per ROW (V-transposed GEMM)
// flat = logical block id in a gx*gy grid (T1-swizzled inside).
// sm = LDS arena, 2*BM*BK + 2*BN*BK u16 (double-buffered A then B).
template <int EPI, int BM, int BN, int BK>
__device__ __forceinline__ void gemm_body(int flat, int gx, int gy,
                                          const u16* __restrict__ A,
                                          const u16* __restrict__ Bt,
                                          const float* __restrict__ bias,
                                          const float* __restrict__ resid,
                                          void* __restrict__ C,
                                          int M, int N, int K, int lda,
                                          u16* sm) {
  constexpr int MT = BM / 32;       // m-frags per wave
  constexpr int NT = BN / 32;       // n-frags per wave
  constexpr int CB = BK / 8;        // colblocks (8 or 16)
  constexpr int RPP = 2048 / BK;    // rows staged per pass (32 or 16)
  constexpr int AP = BM / RPP;      // staging passes
  constexpr int BP = BN / RPP;
  constexpr int KK = BK / 32;       // k-subtiles per buffer
  constexpr int LAU = BM * BK;      // one A buffer, u16
  constexpr int LBU = BN * BK;
  int s_id = xswz(flat, gx * gy);
  int bn = s_id % gx, bm = s_id / gx;
  int t = threadIdx.x;
  int wave = t >> 6, lane = t & 63, quad = lane >> 4, l15 = lane & 15;
  int wm = (wave >> 1) * (BM / 2), wn = (wave & 1) * (BN / 2);
  f32x4 acc[MT][NT] = {};
  int srow = t / CB;
  int scol = ((t % CB) ^ (srow & (CB - 1))) * 8;  // swizzled global colblk
  const u16* Ag = A + (size_t)(bm * BM) * lda;
  const u16* Bg = Bt + (size_t)(bn * BN) * lda;

  auto stage = [&](int k0, int buf) {
    u16* laB = sm + buf * LAU;
    u16* lbB = sm + 2 * LAU + buf * LBU;
#if HAVE_GLDS
    u16* laW = laB + wave * 512;  // lane i -> +16B*i
    u16* lbW = lbB + wave * 512;
#pragma unroll
    for (int g = 0; g < AP; g++)
      glds16(&Ag[(size_t)(srow + g * RPP) * lda + k0 + scol], laW + g * 2048);
#pragma unroll
    for (int g = 0; g < BP; g++)
      glds16(&Bg[(size_t)(srow + g * RPP) * lda + k0 + scol], lbW + g * 2048);
#else
#pragma unroll
    for (int g = 0; g < AP; g++)
      *(bf16x8*)&laB[(srow + g * RPP) * BK + (t % CB) * 8] =
          *(const bf16x8*)&Ag[(size_t)(srow + g * RPP) * lda + k0 + scol];
#pragma unroll
    for (int g = 0; g < BP; g++)
      *(bf16x8*)&lbB[(srow + g * RPP) * BK + (t % CB) * 8] =
          *(const bf16x8*)&Bg[(size_t)(srow + g * RPP) * lda + k0 + scol];
#endif
  };

  stage(0, 0);  // prologue
  const int nk = K / BK;
  int cur = 0;
  for (int ks = 0; ks < nk; ks++) {
    __syncthreads();  // buf[cur] staged & visible
    if (ks + 1 < nk) stage((ks + 1) * BK, cur ^ 1);
    const u16* lac = sm + cur * LAU;
    const u16* lbc = sm + 2 * LAU + cur * LBU;
#pragma unroll
    for (int kk = 0; kk < KK; kk++) {
      bf16x8 af[MT], bfr[NT];
#pragma unroll
      for (int i = 0; i < MT; i++) {
        int row = wm + i * 16 + l15;
        af[i] = *(const bf16x8*)&lac[row * BK + ((kk * 4 + quad) ^ (row & (CB - 1))) * 8];
      }
#pragma unroll
      for (int i = 0; i < NT; i++) {
        int row = wn + i * 16 + l15;
        bfr[i] = *(const bf16x8*)&lbc[row * BK + ((kk * 4 + quad) ^ (row & (CB - 1))) * 8];
      }
#pragma unroll
      for (int mt = 0; mt < MT; mt++)
#pragma unroll
        for (int nt = 0; nt < NT; nt++)
          acc[mt][nt] = __builtin_amdgcn_mfma_f32_16x16x32_bf16(
              af[mt], bfr[nt], acc[mt][nt], 0, 0, 0);
    }
    cur ^= 1;
  }
#pragma unroll
  for (int mt = 0; mt < MT; mt++)
#pragma unroll
    for (int nt = 0; nt < NT; nt++) {
      int col = bn * BN + wn + nt * 16 + l15;
      float bcol = (EPI == 3) ? 0.f : bias[col];
#pragma unroll
      for (int r = 0; r < 4; r++) {
        int row = bm * BM + wm + mt * 16 + quad * 4 + r;
        float v = acc[mt][nt][r] + ((EPI == 3) ? bias[row] : bcol);
        if (EPI == 1) v = fmaxf(v, 0.f);
        if (EPI == 2)
          ((float*)C)[(size_t)row * N + col] = v + resid[(size_t)row * N + col];
        else
          ((u16*)C)[(size_t)row * N + col] = f2bf(v);
      }
    }
}

// Standalone GEMM kernel (per-instantiation LDS sizing)
template <int EPI, int BM, int BN, int BK>
__global__ __launch_bounds__(256) void gemm_bt(const u16* __restrict__ A,
                                               const u16* __restrict__ Bt,
                                               const float* __restrict__ bias,
                                               const float* __restrict__ resid,
                                               void* __restrict__ C,
                                               int M, int N, int K, int lda) {
  __shared__ __align__(16) u16 sm[2 * BM * BK + 2 * BN * BK];
  int flat = blockIdx.x + gridDim.x * blockIdx.y;
  gemm_body<EPI, BM, BN, BK>(flat, gridDim.x, gridDim.y, A, Bt, bias, resid,
                             C, M, N, K, lda, sm);
}

// Fused QK-proj + V^T-proj: two independent GEMMs, one dispatch (1024 blocks)
__global__ __launch_bounds__(256) void qkv_k(const u16* __restrict__ ybuf,
                                             const u16* __restrict__ wq_l,
                                             const float* __restrict__ inb_l,
                                             u16* __restrict__ qk,
                                             u16* __restrict__ vtb) {
  __shared__ __align__(16) u16 sm[32768];  // 64 KB arena (max of both bodies)
  int f = blockIdx.x;
  if (f < 512) {
    // Q|K projection: [4096,1024] = ybuf[4096,512] @ wq[0:1024]^T, 64x128xBK64
    gemm_body<0, 64, 128, 64>(f, 2 * ND / 128, NB * NS / 64, ybuf, wq_l,
                              inb_l, nullptr, qk, NB * NS, 2 * ND, ND, ND, sm);
  } else {
    // V projection, transposed out: [512,4096] = wv[512,512] @ ybuf^T, 64x64xBK128
    gemm_body<3, 64, 64, 128>(f - 512, NB * NS / 64, ND / 64,
                              wq_l + (size_t)2 * ND * ND, ybuf,
                              inb_l + 2 * ND, nullptr, vtb, ND, NB * NS, ND,
                              ND, sm);
  }
}

// ---------------- Flash attention, split-KV, no-max softmax (R18) ----------
// qk: [B*S, 2*D] bf16 (q|k per token). vt: [D, B*S] bf16 (row=h*64+dh).
// 32x32x16 MFMA, 4 waves x 32 q (QBLK=128, 256 thr). Swapped QK^T:
// sc[kt] = mfma(kf, qf) -> C[key][q]: col=l&31=q, row(reg)=key
// (=(r&3)+8*(r>>2)+4*H + 32*kt). Mask (xLOG2E) is the C-init. P stays in
// registers: cvt_pk pairs P2[kt][r2][p] + one shfl_xor(32) per pack rebuild
// the PV A-frags pf[kk] (lane holds P[q=l&31][k=kk*16+H*8+j]). Row-sums via
// VALU + final shfl_xor. PV: oacc[dt]=mfma(pf[kk], vf) -> C[q][dh].
__global__ __launch_bounds__(256) void attn_k(const u16* __restrict__ qk,
                                              const u16* __restrict__ vt,
                                              const float* __restrict__ mask,
                                              u16* __restrict__ opart,
                                              float* __restrict__ lbuf) {
  __shared__ u16 kt_s[64 * 64];  // K tile [key][dim], 8-blk XOR swizzled
  __shared__ u16 vt_s[64 * 64];  // V^T tile [dh][key], swizzled
  __shared__ float mask_s[CK];   // chunk mask * LOG2E
  // hw flat id (x fastest) -> XCD-chunked logical (qt, bh, c)
  int flat = blockIdx.x + 16 * (blockIdx.y + 16 * blockIdx.z);
  int s_id = xswz(flat, 16 * 16 * NCHUNK);
  int qt = s_id & 15;
  int bh = (s_id >> 4) & 15;
  int c = s_id >> 8;
  int b = bh >> 3, h = bh & 7;
  int t = threadIdx.x;
  int wave = t >> 6, lane = t & 63, l31 = lane & 31, H = lane >> 5;
  bool H0 = (H == 0);

  // stage chunk mask once (first __syncthreads in the loop orders it)
  {
    const float* mrow = mask + b * NS + c * CK;
    mask_s[t] = mrow[t] * LOG2E;
    mask_s[t + 256] = mrow[t + 256] * LOG2E;
  }

  // Q fragments (B-operand): lane holds Q[q=l31][kk*16 + H*8 + j]
  int qrow = qt * 128 + wave * 32 + l31;
  const u16* qbase = qk + ((size_t)(b * NS + qrow)) * (2 * ND) + h * NDH;
  bf16x8 qf[4];
#pragma unroll
  for (int kk = 0; kk < 4; kk++) {
    qf[kk] = *(const bf16x8*)&qbase[kk * 16 + H * 8];
#pragma unroll
    for (int e = 0; e < 8; e++) qf[kk][e] = (__bf16)((float)qf[kk][e] * QSCALE);
  }

  f32x16 oacc[2] = {};
  float lhalf = 0.f;  // per-lane partial row-sum (this half's keys)

  int srow8 = t >> 3;                          // [0,32): staged row
  int segsw = ((t & 7) ^ ((t >> 3) & 7)) * 8;  // swizzled fetch colblk
  const u16* kg0 = qk + ((size_t)(b * NS + srow8)) * (2 * ND) + ND + h * NDH + segsw;
  const u16* vg0 = vt + ((size_t)(h * NDH + srow8)) * (NB * NS) + b * NS + segsw;
#if HAVE_GLDS
  u16* ktB = kt_s + wave * 512;
  u16* vtB = vt_s + wave * 512;
#endif
  for (int kt0 = c * CK; kt0 < (c + 1) * CK; kt0 += 64) {
    __syncthreads();
#if HAVE_GLDS
    glds16(&kg0[(size_t)kt0 * (2 * ND)], ktB);
    glds16(&kg0[(size_t)(kt0 + 32) * (2 * ND)], ktB + 2048);
    glds16(&vg0[kt0], vtB);
    glds16(&vg0[kt0 + (size_t)32 * (NB * NS)], vtB + 2048);
#else
    *(bf16x8*)&kt_s[srow8 * 64 + (t & 7) * 8] =
        *(const bf16x8*)&kg0[(size_t)kt0 * (2 * ND)];
    *(bf16x8*)&kt_s[(srow8 + 32) * 64 + (t & 7) * 8] =
        *(const bf16x8*)&kg0[(size_t)(kt0 + 32) * (2 * ND)];
    *(bf16x8*)&vt_s[srow8 * 64 + (t & 7) * 8] = *(const bf16x8*)&vg0[kt0];
    *(bf16x8*)&vt_s[(srow8 + 32) * 64 + (t & 7) * 8] =
        *(const bf16x8*)&vg0[kt0 + (size_t)32 * (NB * NS)];
#endif
    __syncthreads();
    int ktl = kt0 - c * CK;
    // S^T = K @ Q^T per 32-key tile, C-initialized with mask (xLOG2E).
    f32x16 sc[2];
#pragma unroll
    for (int kt = 0; kt < 2; kt++) {
#pragma unroll
      for (int g = 0; g < 4; g++) {
        f32x4 mm = *(const f32x4*)&mask_s[ktl + 32 * kt + 8 * g + 4 * H];
#pragma unroll
        for (int e = 0; e < 4; e++) sc[kt][4 * g + e] = mm[e];
      }
      int row = 32 * kt + l31;  // key row in kt_s
#pragma unroll
      for (int kk = 0; kk < 4; kk++) {
        bf16x8 kf = *(const bf16x8*)&kt_s[row * 64 + (((2 * kk + H) ^ (row & 7)) << 3)];
        sc[kt] = __builtin_amdgcn_mfma_f32_32x32x16_bf16(kf, qf[kk], sc[kt], 0, 0, 0);
      }
    }
    // p = exp2(sc); pack bf16 pairs in-register; accumulate row-sum.
    unsigned p2[2][4][2];
#pragma unroll
    for (int kt = 0; kt < 2; kt++)
#pragma unroll
      for (int r2 = 0; r2 < 4; r2++)
#pragma unroll
        for (int p = 0; p < 2; p++) {
          float e0 = __builtin_amdgcn_exp2f(sc[kt][4 * r2 + 2 * p]);
          float e1 = __builtin_amdgcn_exp2f(sc[kt][4 * r2 + 2 * p + 1]);
          lhalf += e0 + e1;
          float2 pp; pp.x = e0; pp.y = e1;
          __hip_bfloat162 bb = __float22bfloat162_rn(pp);
          p2[kt][r2][p] = *reinterpret_cast<unsigned*>(&bb);
        }
    // Rebuild PV A-frags: pf[kk] lane = P[q=l31][k = kk*16 + H*8 + j].
    // slot a of pf[kk] = P2[kk>>1][2*(kk&1) + H_target][a&1] from half a>>1.
    bf16x8 pfk[4];
#pragma unroll
    for (int kk = 0; kk < 4; kk++) {
      const int kt = kk >> 1;
      const int b0 = 2 * (kk & 1), b1 = b0 + 1;
      unsigned sent0 = H0 ? p2[kt][b1][0] : p2[kt][b0][0];
      unsigned sent1 = H0 ? p2[kt][b1][1] : p2[kt][b0][1];
      unsigned r0 = (unsigned)__shfl_xor((int)sent0, 32);
      unsigned r1 = (unsigned)__shfl_xor((int)sent1, 32);
      uint4 pk;
      pk.x = H0 ? p2[kt][b0][0] : r0;
      pk.y = H0 ? p2[kt][b0][1] : r1;
      pk.z = H0 ? r0 : p2[kt][b1][0];
      pk.w = H0 ? r1 : p2[kt][b1][1];
      pfk[kk] = *reinterpret_cast<bf16x8*>(&pk);
    }
    // O += P @ V  (C[q][dh]: col=l31=dh, row(reg)=q)
#pragma unroll
    for (int dt = 0; dt < 2; dt++) {
      int row = dt * 32 + l31;  // dh row in vt_s
#pragma unroll
      for (int kk = 0; kk < 4; kk++) {
        bf16x8 vf = *(const bf16x8*)&vt_s[row * 64 + (((2 * kk + H) ^ (row & 7)) << 3)];
        oacc[dt] = __builtin_amdgcn_mfma_f32_32x32x16_bf16(pfk[kk], vf, oacc[dt], 0, 0, 0);
      }
    }
  }
  // total row-sum: this half's keys + partner half's
  float lsum = lhalf + (float)__shfl_xor((float)lhalf, 32);
  // store un-normalized partial O (bf16) + l per row
  u16* ob = opart + (((size_t)(c * NB * NH + bh) * NS) + qt * 128 + wave * 32) * NDH;
#pragma unroll
  for (int dt = 0; dt < 2; dt++)
#pragma unroll
    for (int r = 0; r < 16; r++) {
      int q = (r & 3) + 8 * (r >> 2) + 4 * H;
      ob[(size_t)q * NDH + dt * 32 + l31] = f2bf(oacc[dt][r]);
    }
  if (H == 0) {
    size_t li = (size_t)(c * NB * NH + bh) * NS + qt * 128 + wave * 32 + l31;
    lbuf[li] = lsum;
  }
}

// ---------------- merge split-KV partials -> o [B*S, D] bf16 ---------------
__global__ __launch_bounds__(256) void attn_merge(const u16* __restrict__ opart,
                                                  const float* __restrict__ lbuf,
                                                  u16* __restrict__ o) {
  int gt = blockIdx.x * 256 + threadIdx.x;  // [0, 16*2048*8)
  int grp = gt & 7;
  int s = (gt >> 3) & (NS - 1);
  int bh = gt >> 14;
  float L = 0.f;
#pragma unroll
  for (int c = 0; c < NCHUNK; c++)
    L += lbuf[(size_t)(c * NB * NH + bh) * NS + s];
  float inv = 1.0f / L;
  float acc[8] = {};
#pragma unroll
  for (int c = 0; c < NCHUNK; c++) {
    bf16x8 ov = *(const bf16x8*)&opart[((size_t)(c * NB * NH + bh) * NS + s) * NDH + grp * 8];
#pragma unroll
    for (int j = 0; j < 8; j++) acc[j] += (float)ov[j];
  }
  u16x8 res;
#pragma unroll
  for (int j = 0; j < 8; j++) res[j] = f2bf(acc[j] * inv);
  int b = bh >> 3, h = bh & 7;
  *(u16x8*)&o[((size_t)(b * NS + s)) * ND + h * NDH + grp * 8] = res;
}

// ---------------------------------------------------------------------------
extern "C" void kernel_launch(void* const* d_in, const int* in_sizes, int n_in,
                              void* d_out, int out_size, void* d_ws, size_t ws_size,
                              hipStream_t stream) {
  const float* x = (const float*)d_in[0];
  const float* mask = (const float*)d_in[1];
  const float* ln1w = (const float*)d_in[2];
  const float* ln1b = (const float*)d_in[3];
  const float* in_w = (const float*)d_in[4];
  const float* in_b = (const float*)d_in[5];
  const float* out_w = (const float*)d_in[6];
  const float* out_b = (const float*)d_in[7];
  const float* ln2w = (const float*)d_in[8];
  const float* ln2b = (const float*)d_in[9];
  const float* f1w = (const float*)d_in[10];
  const float* f1b = (const float*)d_in[11];
  const float* f2w = (const float*)d_in[12];
  const float* f2b = (const float*)d_in[13];
  const float* normw = (const float*)d_in[14];
  const float* normb = (const float*)d_in[15];

  char* ws = (char*)d_ws;
  auto carve = [&](size_t bytes) {
    char* p = ws;
    ws += (bytes + 255) & ~(size_t)255;
    return p;
  };
  u16* wq_t = (u16*)carve((size_t)NL * 3 * ND * ND * 2);   // [L][3D][D]
  u16* wo_t = (u16*)carve((size_t)NL * ND * ND * 2);       // [L][D][D]
  u16* w1_t = (u16*)carve((size_t)NL * NF * ND * 2);       // [L][F][D]
  u16* w2_t = (u16*)carve((size_t)NL * ND * NF * 2);       // [L][D][F]
  u16* ybuf = (u16*)carve((size_t)NB * NS * ND * 2);
  u16* qk = (u16*)carve((size_t)NB * NS * 2 * ND * 2);     // [M][2D]
  u16* vtb = (u16*)carve((size_t)ND * NB * NS * 2);        // [D][M]
  u16* obuf = (u16*)carve((size_t)NB * NS * ND * 2);
  u16* ubuf = (u16*)carve((size_t)NB * NS * NF * 2);       // FFN mid; aliased by opart
  float* hA = (float*)carve((size_t)NB * NS * ND * 4);
  float* hB = (float*)carve((size_t)NB * NS * ND * 4);
  float* lbuf = (float*)carve((size_t)NCHUNK * NB * NH * NS * 4);
  u16* opart = ubuf;  // same size (16.8 MB), disjoint lifetime within a layer

  const int M = NB * NS;  // 4096
  dim3 tb(32, 8);
  wcvt_t<<<dim3(3 * ND / 32, ND / 32, NL), tb, 0, stream>>>(in_w, wq_t, ND, 3 * ND);
  wcvt_t<<<dim3(ND / 32, ND / 32, NL), tb, 0, stream>>>(out_w, wo_t, ND, ND);
  wcvt_t<<<dim3(NF / 32, ND / 32, NL), tb, 0, stream>>>(f1w, w1_t, ND, NF);
  wcvt_t<<<dim3(ND / 32, NF / 32, NL), tb, 0, stream>>>(f2w, w2_t, NF, ND);

  const float* hin = x;
  for (int l = 0; l < NL; l++) {
    ln_k<1><<<M, 256, 0, stream>>>(hin, ln1w + l * ND, ln1b + l * ND, ybuf);
    // Fused Q|K projection + V^T projection: 1024 blocks, one dispatch
    qkv_k<<<1024, 256, 0, stream>>>(ybuf, wq_t + (size_t)l * 3 * ND * ND,
                                    in_b + (size_t)l * 3 * ND, qk, vtb);
    // attn: 32x32 MFMA, QBLK=128, 256 threads, grid 16x16x4 = 1024 blocks
    attn_k<<<dim3(NS / 128, NB * NH, NCHUNK), 256, 0, stream>>>(
        qk, vtb, mask, opart, lbuf);
    attn_merge<<<(NB * NH * NS * 8) / 256, 256, 0, stream>>>(opart, lbuf, obuf);
    // O projection: [4096,512] -- 64x64xBK128 dbuf, grid 512
    gemm_bt<2, 64, 64, 128><<<dim3(ND / 64, M / 64), 256, 0, stream>>>(
        obuf, wo_t + (size_t)l * ND * ND, out_b + l * ND, hin, hB, M, ND, ND, ND);
    ln_k<1><<<M, 256, 0, stream>>>(hB, ln2w + l * ND, ln2b + l * ND, ybuf);
    // FFN1: [4096,2048] -- 128x128xBK64 dbuf, grid 512
    gemm_bt<1, 128, 128, 64><<<dim3(NF / 128, M / 128), 256, 0, stream>>>(
        ybuf, w1_t + (size_t)l * NF * ND, f1b + l * NF, nullptr, ubuf,
        M, NF, ND, ND);
    // FFN2: [4096,512] -- 64x64xBK128 dbuf, grid 512
    gemm_bt<2, 64, 64, 128><<<dim3(ND / 64, M / 64), 256, 0, stream>>>(
        ubuf, w2_t + (size_t)l * ND * NF, f2b + l * ND, hB, hA, M, ND, NF, NF);
    hin = hA;
  }
  ln_k<0><<<M, 256, 0, stream>>>(hA, normw, normb, (float*)d_out);
}